// Round 5
// baseline (205.612 us; speedup 1.0000x reference)
//
#include <hip/hip_runtime.h>

#define GRID  2048
#define BLOCK 256
#define UNROLL 4

typedef float f4 __attribute__((ext_vector_type(4)));
typedef int   i4 __attribute__((ext_vector_type(4)));

// ws layout: [0..GRID)        pos partials (f32)
//            [GRID..2*GRID)   neg partials (f32)
//            [2*GRID..3*GRID) pos counts  (u32)
//            [3*GRID]         completion ticket (u32, memset to 0 each launch)

__device__ __forceinline__ void proc_elem(float pv, int tv,
                                          float& posd, float& allsp, float& possp,
                                          float& cntf)
{
    float a    = fabsf(pv);
    float em   = __expf(-a);            // exp(-|p|) in (0,1]
    float lc   = __logf(1.0f + em);     // log1p(exp(-|p|)), stable
    float sp   = fmaxf(pv, 0.0f) + lc;  // softplus(p)
    float diff = sp - pv;               // softplus(-p)
    float t    = (float)tv;             // tv in {0,1}
    posd  = fmaf(t, diff, posd);        // sum over pos of softplus(-p)
    allsp += sp;                        // sum over all of softplus(p)
    possp = fmaf(t, sp, possp);         // sum over pos of softplus(p)
    cntf  += t;
}

__global__ __launch_bounds__(BLOCK) void formicro_reduce(
    const f4* __restrict__ pred4,
    const i4* __restrict__ ty4,
    int n4,
    const float* __restrict__ pred_s,
    const int*   __restrict__ ty_s,
    int n,
    float* __restrict__ ws,
    float* __restrict__ out,
    float total)
{
    const int T   = gridDim.x * blockDim.x;
    const int gid = blockIdx.x * blockDim.x + threadIdx.x;

    float posd = 0.f, allsp = 0.f, possp = 0.f, cntf = 0.f;

    const int nfull = n4 / (UNROLL * T);
    int i = gid;
    for (int g = 0; g < nfull; ++g) {
        f4 P[UNROLL];
        i4 L[UNROLL];
        #pragma unroll
        for (int u = 0; u < UNROLL; ++u) { P[u] = pred4[i + u * T]; }
        #pragma unroll
        for (int u = 0; u < UNROLL; ++u) { L[u] = ty4[i + u * T]; }
        #pragma unroll
        for (int u = 0; u < UNROLL; ++u) {
            proc_elem(P[u][0], L[u][0], posd, allsp, possp, cntf);
            proc_elem(P[u][1], L[u][1], posd, allsp, possp, cntf);
            proc_elem(P[u][2], L[u][2], posd, allsp, possp, cntf);
            proc_elem(P[u][3], L[u][3], posd, allsp, possp, cntf);
        }
        i += UNROLL * T;
    }
    for (; i < n4; i += T) {          // leftover float4s (dead at 8192^2)
        f4 p = pred4[i];
        i4 t = ty4[i];
        proc_elem(p[0], t[0], posd, allsp, possp, cntf);
        proc_elem(p[1], t[1], posd, allsp, possp, cntf);
        proc_elem(p[2], t[2], posd, allsp, possp, cntf);
        proc_elem(p[3], t[3], posd, allsp, possp, cntf);
    }
    for (int k = (n4 << 2) + gid; k < n; k += T) {   // scalar tail
        proc_elem(pred_s[k], ty_s[k], posd, allsp, possp, cntf);
    }

    float negs = allsp - possp;   // sum over neg of softplus(p)

    // wave-64 reduction
    #pragma unroll
    for (int off = 32; off > 0; off >>= 1) {
        posd += __shfl_down(posd, off);
        negs += __shfl_down(negs, off);
        cntf += __shfl_down(cntf, off);
    }

    __shared__ float spos[BLOCK / 64];
    __shared__ float sneg[BLOCK / 64];
    __shared__ float scnt[BLOCK / 64];
    __shared__ int   s_last;
    const int wid  = threadIdx.x >> 6;
    const int lane = threadIdx.x & 63;
    if (lane == 0) { spos[wid] = posd; sneg[wid] = negs; scnt[wid] = cntf; }
    __syncthreads();

    unsigned* ticket = (unsigned*)ws + 3 * GRID;
    if (threadIdx.x == 0) {
        float P = 0.f, Ng = 0.f, C = 0.f;
        #pragma unroll
        for (int w = 0; w < BLOCK / 64; ++w) { P += spos[w]; Ng += sneg[w]; C += scnt[w]; }
        ws[blockIdx.x]        = P;
        ws[GRID + blockIdx.x] = Ng;
        ((unsigned*)ws)[2 * GRID + blockIdx.x] = (unsigned)C;  // <= 32768, exact
        __threadfence();                       // release: partials visible device-wide
        unsigned done = atomicAdd(ticket, 1u); // device-scope by default
        s_last = (done == GRID - 1);
    }
    __syncthreads();

    if (s_last) {
        __threadfence();   // acquire: see all blocks' partials
        float fposd = 0.f, fnegs = 0.f;
        unsigned fcnt = 0;
        for (int k = threadIdx.x; k < GRID; k += BLOCK) {
            fposd += ws[k];
            fnegs += ws[GRID + k];
            fcnt  += ((const unsigned*)ws)[2 * GRID + k];
        }
        #pragma unroll
        for (int off = 32; off > 0; off >>= 1) {
            fposd += __shfl_down(fposd, off);
            fnegs += __shfl_down(fnegs, off);
            fcnt  += __shfl_down(fcnt, off);
        }
        __shared__ float    fp[BLOCK / 64];
        __shared__ float    fn[BLOCK / 64];
        __shared__ unsigned fc[BLOCK / 64];
        if (lane == 0) { fp[wid] = fposd; fn[wid] = fnegs; fc[wid] = fcnt; }
        __syncthreads();
        if (threadIdx.x == 0) {
            float P = 0.f, Ng = 0.f;
            unsigned C = 0;
            #pragma unroll
            for (int w = 0; w < BLOCK / 64; ++w) { P += fp[w]; Ng += fn[w]; C += fc[w]; }
            float npos = (float)C;
            float nneg = total - npos;
            out[0] = P / npos + Ng / nneg;
        }
    }
}

extern "C" void kernel_launch(void* const* d_in, const int* in_sizes, int n_in,
                              void* d_out, int out_size, void* d_ws, size_t ws_size,
                              hipStream_t stream)
{
    const float* pred = (const float*)d_in[0];
    const int*   ty   = (const int*)d_in[1];
    float*       out  = (float*)d_out;
    float*       ws   = (float*)d_ws;

    int n  = in_sizes[0];   // 8192*8192 = 67108864
    int n4 = n >> 2;

    // zero only the 4-byte completion ticket (ws is poisoned once, never re-poisoned)
    hipMemsetAsync((char*)d_ws + 3 * GRID * sizeof(float), 0, sizeof(unsigned), stream);

    formicro_reduce<<<GRID, BLOCK, 0, stream>>>(
        (const f4*)pred, (const i4*)ty, n4, pred, ty, n, ws, out, (float)n);
}

// Round 6
// 113.386 us; speedup vs baseline: 1.8134x; 1.8134x over previous
//
#include <hip/hip_runtime.h>

#define GRID  2048
#define BLOCK 256
#define UNROLL 4

typedef float f4 __attribute__((ext_vector_type(4)));
typedef int   i4 __attribute__((ext_vector_type(4)));

// ws layout: [0..GRID)        pos partials (f32)
//            [GRID..2*GRID)   neg partials (f32)
//            [2*GRID..3*GRID) pos counts  (u32)

__device__ __forceinline__ void proc_elem(float pv, int tv,
                                          float& posd, float& allsp, float& possp,
                                          float& cntf)
{
    float a    = fabsf(pv);
    float em   = __expf(-a);            // exp(-|p|) in (0,1]
    float lc   = __logf(1.0f + em);     // log1p(exp(-|p|)), stable
    float sp   = fmaxf(pv, 0.0f) + lc;  // softplus(p)
    float diff = sp - pv;               // softplus(-p)
    float t    = (float)tv;             // tv in {0,1}
    posd  = fmaf(t, diff, posd);        // sum over pos of softplus(-p)
    allsp += sp;                        // sum over all of softplus(p)
    possp = fmaf(t, sp, possp);         // sum over pos of softplus(p)
    cntf  += t;
}

__global__ __launch_bounds__(BLOCK) void formicro_reduce(
    const f4* __restrict__ pred4,
    const i4* __restrict__ ty4,
    int n4,
    const float* __restrict__ pred_s,
    const int*   __restrict__ ty_s,
    int n,
    float* __restrict__ ws)
{
    const int T   = gridDim.x * blockDim.x;
    const int gid = blockIdx.x * blockDim.x + threadIdx.x;

    float posd = 0.f, allsp = 0.f, possp = 0.f, cntf = 0.f;

    const int nfull = n4 / (UNROLL * T);
    int i = gid;
    for (int g = 0; g < nfull; ++g) {
        f4 P[UNROLL];
        i4 L[UNROLL];
        #pragma unroll
        for (int u = 0; u < UNROLL; ++u) { P[u] = pred4[i + u * T]; }
        #pragma unroll
        for (int u = 0; u < UNROLL; ++u) { L[u] = ty4[i + u * T]; }
        #pragma unroll
        for (int u = 0; u < UNROLL; ++u) {
            proc_elem(P[u][0], L[u][0], posd, allsp, possp, cntf);
            proc_elem(P[u][1], L[u][1], posd, allsp, possp, cntf);
            proc_elem(P[u][2], L[u][2], posd, allsp, possp, cntf);
            proc_elem(P[u][3], L[u][3], posd, allsp, possp, cntf);
        }
        i += UNROLL * T;
    }
    for (; i < n4; i += T) {          // leftover float4s (dead at 8192^2)
        f4 p = pred4[i];
        i4 t = ty4[i];
        proc_elem(p[0], t[0], posd, allsp, possp, cntf);
        proc_elem(p[1], t[1], posd, allsp, possp, cntf);
        proc_elem(p[2], t[2], posd, allsp, possp, cntf);
        proc_elem(p[3], t[3], posd, allsp, possp, cntf);
    }
    for (int k = (n4 << 2) + gid; k < n; k += T) {   // scalar tail
        proc_elem(pred_s[k], ty_s[k], posd, allsp, possp, cntf);
    }

    float negs = allsp - possp;   // sum over neg of softplus(p)

    // wave-64 reduction
    #pragma unroll
    for (int off = 32; off > 0; off >>= 1) {
        posd += __shfl_down(posd, off);
        negs += __shfl_down(negs, off);
        cntf += __shfl_down(cntf, off);
    }

    __shared__ float spos[BLOCK / 64];
    __shared__ float sneg[BLOCK / 64];
    __shared__ float scnt[BLOCK / 64];
    const int wid  = threadIdx.x >> 6;
    const int lane = threadIdx.x & 63;
    if (lane == 0) { spos[wid] = posd; sneg[wid] = negs; scnt[wid] = cntf; }
    __syncthreads();

    if (threadIdx.x == 0) {
        float P = 0.f, Ng = 0.f, C = 0.f;
        #pragma unroll
        for (int w = 0; w < BLOCK / 64; ++w) { P += spos[w]; Ng += sneg[w]; C += scnt[w]; }
        ws[blockIdx.x]        = P;
        ws[GRID + blockIdx.x] = Ng;
        ((unsigned*)ws)[2 * GRID + blockIdx.x] = (unsigned)C;  // <= 32768, exact
    }
}

__global__ __launch_bounds__(BLOCK) void formicro_finalize(
    const float* __restrict__ ws, float* __restrict__ out, float total)
{
    float posd = 0.f, negs = 0.f;
    unsigned cnt = 0;
    for (int i = threadIdx.x; i < GRID; i += BLOCK) {
        posd += ws[i];
        negs += ws[GRID + i];
        cnt  += ((const unsigned*)ws)[2 * GRID + i];
    }
    #pragma unroll
    for (int off = 32; off > 0; off >>= 1) {
        posd += __shfl_down(posd, off);
        negs += __shfl_down(negs, off);
        cnt  += __shfl_down(cnt, off);
    }
    __shared__ float    spos[BLOCK / 64];
    __shared__ float    sneg[BLOCK / 64];
    __shared__ unsigned scnt[BLOCK / 64];
    const int wid  = threadIdx.x >> 6;
    const int lane = threadIdx.x & 63;
    if (lane == 0) { spos[wid] = posd; sneg[wid] = negs; scnt[wid] = cnt; }
    __syncthreads();
    if (threadIdx.x == 0) {
        float P = 0.f, Ng = 0.f;
        unsigned C = 0;
        #pragma unroll
        for (int w = 0; w < BLOCK / 64; ++w) { P += spos[w]; Ng += sneg[w]; C += scnt[w]; }
        float npos = (float)C;
        float nneg = total - npos;
        out[0] = P / npos + Ng / nneg;
    }
}

extern "C" void kernel_launch(void* const* d_in, const int* in_sizes, int n_in,
                              void* d_out, int out_size, void* d_ws, size_t ws_size,
                              hipStream_t stream)
{
    const float* pred = (const float*)d_in[0];
    const int*   ty   = (const int*)d_in[1];
    float*       out  = (float*)d_out;
    float*       ws   = (float*)d_ws;

    int n  = in_sizes[0];   // 8192*8192 = 67108864
    int n4 = n >> 2;

    formicro_reduce<<<GRID, BLOCK, 0, stream>>>(
        (const f4*)pred, (const i4*)ty, n4, pred, ty, n, ws);

    formicro_finalize<<<1, BLOCK, 0, stream>>>(ws, out, (float)n);
}

// Round 7
// 103.903 us; speedup vs baseline: 1.9789x; 1.0913x over previous
//
#include <hip/hip_runtime.h>

#define GRID  2048
#define BLOCK 256

typedef float f4 __attribute__((ext_vector_type(4)));
typedef int   i4 __attribute__((ext_vector_type(4)));

// ws layout: [0..GRID)        pos partials (f32)
//            [GRID..2*GRID)   neg partials (f32)
//            [2*GRID..3*GRID) pos counts  (u32)

__device__ __forceinline__ void proc_elem(float pv, int tv,
                                          float& posd, float& allsp, float& possp,
                                          float& cntf)
{
    float a    = fabsf(pv);
    float em   = __expf(-a);            // exp(-|p|) in (0,1]
    float lc   = __logf(1.0f + em);     // log1p(exp(-|p|)), stable
    float sp   = fmaxf(pv, 0.0f) + lc;  // softplus(p)
    float diff = sp - pv;               // softplus(-p)
    float t    = (float)tv;             // tv in {0,1}
    posd  = fmaf(t, diff, posd);        // sum over pos of softplus(-p)
    allsp += sp;                        // sum over all of softplus(p)
    possp = fmaf(t, sp, possp);         // sum over pos of softplus(p)
    cntf  += t;
}

__device__ __forceinline__ void proc4(const f4 p, const i4 t,
                                      float& posd, float& allsp, float& possp,
                                      float& cntf)
{
    proc_elem(p[0], t[0], posd, allsp, possp, cntf);
    proc_elem(p[1], t[1], posd, allsp, possp, cntf);
    proc_elem(p[2], t[2], posd, allsp, possp, cntf);
    proc_elem(p[3], t[3], posd, allsp, possp, cntf);
}

__global__ __launch_bounds__(BLOCK) void formicro_reduce(
    const f4* __restrict__ pred4,
    const i4* __restrict__ ty4,
    int n4,
    const float* __restrict__ pred_s,
    const int*   __restrict__ ty_s,
    int n,
    float* __restrict__ ws)
{
    const int T   = gridDim.x * blockDim.x;
    const int gid = blockIdx.x * blockDim.x + threadIdx.x;

    float posd = 0.f, allsp = 0.f, possp = 0.f, cntf = 0.f;

    // software-pipelined main loop: group = 2 x (float4,int4); prefetch one
    // group ahead so 4 loads are ALWAYS in flight during compute.
    const int iters = n4 / (2 * T);   // 16 at 8192^2
    int i = gid;
    if (iters > 0) {
        f4 P0 = pred4[i], P1 = pred4[i + T];
        i4 L0 = ty4[i],   L1 = ty4[i + T];
        i += 2 * T;
        for (int g = 0; g < iters - 1; ++g) {
            f4 Q0 = pred4[i];
            f4 Q1 = pred4[i + T];
            i4 M0 = ty4[i];
            i4 M1 = ty4[i + T];
            proc4(P0, L0, posd, allsp, possp, cntf);
            proc4(P1, L1, posd, allsp, possp, cntf);
            P0 = Q0; P1 = Q1; L0 = M0; L1 = M1;
            i += 2 * T;
        }
        proc4(P0, L0, posd, allsp, possp, cntf);
        proc4(P1, L1, posd, allsp, possp, cntf);
    }
    // leftover float4s (dead at 8192^2 but kept for generality)
    for (; i < n4; i += T) {
        f4 p = pred4[i];
        i4 t = ty4[i];
        proc4(p, t, posd, allsp, possp, cntf);
    }
    // scalar tail (n % 4)
    for (int k = (n4 << 2) + gid; k < n; k += T) {
        proc_elem(pred_s[k], ty_s[k], posd, allsp, possp, cntf);
    }

    float negs = allsp - possp;   // sum over neg of softplus(p)

    // wave-64 reduction
    #pragma unroll
    for (int off = 32; off > 0; off >>= 1) {
        posd += __shfl_down(posd, off);
        negs += __shfl_down(negs, off);
        cntf += __shfl_down(cntf, off);
    }

    __shared__ float spos[BLOCK / 64];
    __shared__ float sneg[BLOCK / 64];
    __shared__ float scnt[BLOCK / 64];
    const int wid  = threadIdx.x >> 6;
    const int lane = threadIdx.x & 63;
    if (lane == 0) { spos[wid] = posd; sneg[wid] = negs; scnt[wid] = cntf; }
    __syncthreads();

    if (threadIdx.x == 0) {
        float P = 0.f, Ng = 0.f, C = 0.f;
        #pragma unroll
        for (int w = 0; w < BLOCK / 64; ++w) { P += spos[w]; Ng += sneg[w]; C += scnt[w]; }
        ws[blockIdx.x]        = P;
        ws[GRID + blockIdx.x] = Ng;
        ((unsigned*)ws)[2 * GRID + blockIdx.x] = (unsigned)C;  // <= 32768, exact
    }
}

__global__ __launch_bounds__(BLOCK) void formicro_finalize(
    const float* __restrict__ ws, float* __restrict__ out, float total)
{
    float posd = 0.f, negs = 0.f;
    unsigned cnt = 0;
    for (int i = threadIdx.x; i < GRID; i += BLOCK) {
        posd += ws[i];
        negs += ws[GRID + i];
        cnt  += ((const unsigned*)ws)[2 * GRID + i];
    }
    #pragma unroll
    for (int off = 32; off > 0; off >>= 1) {
        posd += __shfl_down(posd, off);
        negs += __shfl_down(negs, off);
        cnt  += __shfl_down(cnt, off);
    }
    __shared__ float    spos[BLOCK / 64];
    __shared__ float    sneg[BLOCK / 64];
    __shared__ unsigned scnt[BLOCK / 64];
    const int wid  = threadIdx.x >> 6;
    const int lane = threadIdx.x & 63;
    if (lane == 0) { spos[wid] = posd; sneg[wid] = negs; scnt[wid] = cnt; }
    __syncthreads();
    if (threadIdx.x == 0) {
        float P = 0.f, Ng = 0.f;
        unsigned C = 0;
        #pragma unroll
        for (int w = 0; w < BLOCK / 64; ++w) { P += spos[w]; Ng += sneg[w]; C += scnt[w]; }
        float npos = (float)C;
        float nneg = total - npos;
        out[0] = P / npos + Ng / nneg;
    }
}

extern "C" void kernel_launch(void* const* d_in, const int* in_sizes, int n_in,
                              void* d_out, int out_size, void* d_ws, size_t ws_size,
                              hipStream_t stream)
{
    const float* pred = (const float*)d_in[0];
    const int*   ty   = (const int*)d_in[1];
    float*       out  = (float*)d_out;
    float*       ws   = (float*)d_ws;

    int n  = in_sizes[0];   // 8192*8192 = 67108864
    int n4 = n >> 2;

    formicro_reduce<<<GRID, BLOCK, 0, stream>>>(
        (const f4*)pred, (const i4*)ty, n4, pred, ty, n, ws);

    formicro_finalize<<<1, BLOCK, 0, stream>>>(ws, out, (float)n);
}